// Round 8
// baseline (177.948 us; speedup 1.0000x reference)
//
#include <hip/hip_runtime.h>
#include <math.h>

#define SEQ 8
#define NCLASS 10

typedef float v2f __attribute__((ext_vector_type(2)));

__device__ __forceinline__ v2f pkfma(v2f a, v2f b, v2f c) {
    return __builtin_elementwise_fma(a, b, c);
}

__device__ inline float2 cmul(float2 a, float2 b) {
    return make_float2(a.x * b.x - a.y * b.y, a.x * b.y + a.y * b.x);
}

// ---------------------------------------------------------------------------
// build_w: W = G32...G1. One WAVE per column, column in registers
// (4 complex/lane); gate params hoisted to LDS (R7). NEW: output ROW-major
// float4 pairs Wr4[I*128 + u] = (W[I][2u], W[I][2u+1]) via an LDS transpose,
// so the fused evolve reads each lane's k-run as 512 contiguous bytes.
// ---------------------------------------------------------------------------
__global__ __launch_bounds__(256) void build_w_kernel(
    const float* __restrict__ qrot, const float* __restrict__ qent,
    float4* __restrict__ Wr4) {
    __shared__ float4 US[32][2];
    __shared__ int    metaS[32];
    __shared__ float2 colS[4][256];
    const int t = threadIdx.x;
    if (t < 32) {
        const int l = t >> 4, wi = t & 15;
        int bc = -1, qt;
        const float* p;
        if (wi < 8) { qt = wi; p = qrot + (l * 8 + wi) * 3; }
        else { const int qc = wi - 8; qt = (qc + 1) & 7; p = qent + (l * 8 + qc) * 3; bc = 7 - qc; }
        const float th = p[0], ph = p[1], lam = p[2];
        const float c = cosf(0.5f * th), s = sinf(0.5f * th);
        US[t][0] = make_float4(c, 0.0f, -cosf(lam) * s, -sinf(lam) * s);
        US[t][1] = make_float4(cosf(ph) * s, sinf(ph) * s,
                               cosf(ph + lam) * c, sinf(ph + lam) * c);
        metaS[t] = ((bc + 1) << 8) | (7 - qt);
    }
    __syncthreads();

    const int lane = t & 63;
    const int wid = t >> 6;
    const int col = blockIdx.x * 4 + wid;
    const int rbase = lane * 4;
    float2 a[4];
#pragma unroll
    for (int i = 0; i < 4; ++i)
        a[i] = make_float2((rbase + i) == col ? 1.0f : 0.0f, 0.0f);

    for (int g = 0; g < 32; ++g) {
        const int meta = metaS[g];
        const int bt = meta & 255;
        const int bcp1 = meta >> 8;          // 0 = no control
        const float4 u0 = US[g][0];
        const float4 u1 = US[g][1];
        const float2 U00 = make_float2(u0.x, u0.y);
        const float2 U01 = make_float2(u0.z, u0.w);
        const float2 U10 = make_float2(u1.x, u1.y);
        const float2 U11 = make_float2(u1.z, u1.w);
        const int mt = 1 << bt;
        if (bt >= 2) {
            const int pl = mt >> 2;
            const int side = (lane >> (bt - 2)) & 1;
            float2 br[4];
#pragma unroll
            for (int i = 0; i < 4; ++i) {
                br[i].x = __shfl_xor(a[i].x, pl, 64);
                br[i].y = __shfl_xor(a[i].y, pl, 64);
            }
#pragma unroll
            for (int i = 0; i < 4; ++i) {
                const int r = rbase + i;
                float2 na, tt;
                if (side) { na = cmul(U10, br[i]); tt = cmul(U11, a[i]); }
                else      { na = cmul(U00, a[i]); tt = cmul(U01, br[i]); }
                na.x += tt.x; na.y += tt.y;
                const bool act = (bcp1 == 0) || ((r >> (bcp1 - 1)) & 1);
                if (act) a[i] = na;
            }
        } else {
#pragma unroll
            for (int i0 = 0; i0 < 4; ++i0) {
                if (i0 & mt) continue;
                const int i1 = i0 | mt;
                const int r0 = rbase + i0;
                const bool act = (bcp1 == 0) || ((r0 >> (bcp1 - 1)) & 1);
                const float2 a0 = a[i0], a1 = a[i1];
                float2 n0 = cmul(U00, a0), t1 = cmul(U01, a1);
                n0.x += t1.x; n0.y += t1.y;
                float2 n1 = cmul(U10, a0), t2 = cmul(U11, a1);
                n1.x += t2.x; n1.y += t2.y;
                if (act) { a[i0] = n0; a[i1] = n1; }
            }
        }
    }
    // LDS transpose: colS[wid][row] = column entries, then emit row-major.
#pragma unroll
    for (int i = 0; i < 4; ++i) colS[wid][rbase + i] = a[i];
    __syncthreads();
    const int u0 = blockIdx.x * 2;   // block owns u slots u0, u0+1 of every row
    const float2 c0 = colS[0][t], c1 = colS[1][t], c2 = colS[2][t], c3 = colS[3][t];
    Wr4[t * 128 + u0]     = make_float4(c0.x, c0.y, c1.x, c1.y);
    Wr4[t * 128 + u0 + 1] = make_float4(c2.x, c2.y, c3.x, c3.y);
}

// ---------------------------------------------------------------------------
// Per-lane Wv tile piece: acc[jj] = sum_k W[I][(4g+jj)*16+k] * w16[k],
// reading 32 contiguous float4 (512B) from Wr4; writes 2 swizzled b128.
// ---------------------------------------------------------------------------
__device__ __forceinline__ void compute_wv_piece(
    const float4* __restrict__ wr,     // Wr4 + (16f+r)*128 + 32g
    const float* __restrict__ w16row,  // &w16S[t1][0] (LDS, 16B-aligned)
    float4* __restrict__ dst0,         // &WvS4[nbuf][f][r][(2g)^rs]
    float4* __restrict__ dst1) {       // &WvS4[nbuf][f][r][(2g+1)^rs]
    v2f w2[8];
    const float4* wp = (const float4*)w16row;
#pragma unroll
    for (int i = 0; i < 4; ++i) {
        const float4 v = wp[i];
        w2[2 * i]     = (v2f){v.x, v.y};
        w2[2 * i + 1] = (v2f){v.z, v.w};
    }
    v2f acc0 = {0,0}, acc1 = {0,0}, acc2 = {0,0}, acc3 = {0,0};
#pragma unroll
    for (int s = 0; s < 32; ++s) {
        const float4 Wc = wr[s];
        const v2f wk = w2[s & 7];
        const v2f k0 = {wk.x, wk.x}, k1 = {wk.y, wk.y};
        const v2f wa = {Wc.x, Wc.y}, wb = {Wc.z, Wc.w};
        if ((s >> 3) == 0) { acc0 = pkfma(wa, k0, acc0); acc0 = pkfma(wb, k1, acc0); }
        if ((s >> 3) == 1) { acc1 = pkfma(wa, k0, acc1); acc1 = pkfma(wb, k1, acc1); }
        if ((s >> 3) == 2) { acc2 = pkfma(wa, k0, acc2); acc2 = pkfma(wb, k1, acc2); }
        if ((s >> 3) == 3) { acc3 = pkfma(wa, k0, acc3); acc3 = pkfma(wb, k1, acc3); }
    }
    *dst0 = make_float4(acc0.x, acc0.y, acc1.x, acc1.y);
    *dst1 = make_float4(acc2.x, acc2.y, acc3.x, acc3.y);
}

// ---------------------------------------------------------------------------
// evolve (FUSED): 64 blocks x 1024 threads; wave = traced index f.
// R8: wv_kernel folded in — each step's Wv(t+1) tile is computed from Wr4
// (L2-resident, 512B contiguous per lane) during the tail phase and written
// reg-staged+swizzled into the double-buffered WvS4. No WvT buffer, no
// gload_lds, one fewer kernel in the graph.
// ---------------------------------------------------------------------------
__global__ __launch_bounds__(1024)
__attribute__((amdgpu_waves_per_eu(4, 4)))
void evolve_kernel(
    const float* __restrict__ x, const float* __restrict__ g_raw_p,
    const float* __restrict__ fc_w, const float* __restrict__ fc_b,
    const float4* __restrict__ Wr4, float* __restrict__ out) {
    __shared__ float4 WvS4[2][16][16][8];   // [buf][f][row][u ^ (row&7)]
    __shared__ float4 SSp4[16][16][8];      // swizzled same way
    __shared__ float2 redS[16][16];
    __shared__ float dvalS[256];
    __shared__ float dephS[8];
    __shared__ float featsS[64];
    __shared__ float w16S[SEQ][16];

    const int tid = threadIdx.x;
    const int b = blockIdx.x;
    const int f = tid >> 6;
    const int lane = tid & 63;
    const int r = lane >> 2;
    const int g = lane & 3;
    const int rs = r & 7;

    if (tid < 256) redS[tid >> 4][tid & 15] = make_float2(tid == 0 ? 1.0f : 0.0f, 0.0f);
    const float gg = log1pf(expf(g_raw_p[0]));   // softplus
    if (tid < 8) dephS[tid] = expf(-0.5f * gg * gg * (float)tid);
    // all 8 steps' encoding amplitudes up front
    if (tid < 128) {
        const int tt = tid >> 4, k = tid & 15;
        float prod = 1.0f;
#pragma unroll
        for (int i = 0; i < 4; ++i) {
            const float xv = x[(b * SEQ + tt) * 4 + i];
            prod *= ((k >> i) & 1) ? sqrtf(xv) : sqrtf(1.0f - xv);
        }
        w16S[tt][k] = prod;
    }
    __syncthreads();

    const float4* wrBase = Wr4 + (16 * f + r) * 128 + 32 * g;

    // prologue: Wv(0) into buf 0
    compute_wv_piece(wrBase, &w16S[0][0],
                     &WvS4[0][f][r][(2 * g) ^ rs], &WvS4[0][f][r][(2 * g + 1) ^ rs]);
    __syncthreads();

    for (int t = 0; t < SEQ; ++t) {
        const int buf = t & 1;

        // ---- H phase: split accumulators, packed FMAs
        v2f A0 = {0,0}, A1 = {0,0}, A2 = {0,0}, A3 = {0,0};
        v2f B0 = {0,0}, B1 = {0,0}, B2 = {0,0}, B3 = {0,0};
#pragma unroll
        for (int u = 0; u < 8; ++u) {
            const float4 wv = WvS4[buf][f][r][u ^ rs];   // Wv[r][2u], Wv[r][2u+1]
            const float4 ra = *(const float4*)&redS[2 * u][4 * g];
            const float4 rb = *(const float4*)&redS[2 * u][4 * g + 2];
            const float4 rc = *(const float4*)&redS[2 * u + 1][4 * g];
            const float4 rd = *(const float4*)&redS[2 * u + 1][4 * g + 2];
            const v2f wx = {wv.x, wv.x}, wy = {wv.y, wv.y};
            const v2f wz = {wv.z, wv.z}, ww = {wv.w, wv.w};
            const v2f ra0 = {ra.x, ra.y}, ra1 = {ra.z, ra.w};
            const v2f rb0 = {rb.x, rb.y}, rb1 = {rb.z, rb.w};
            const v2f rc0 = {rc.x, rc.y}, rc1 = {rc.z, rc.w};
            const v2f rd0 = {rd.x, rd.y}, rd1 = {rd.z, rd.w};
            A0 = pkfma(wx, ra0, A0);  B0 = pkfma(wy, ra0, B0);
            A1 = pkfma(wx, ra1, A1);  B1 = pkfma(wy, ra1, B1);
            A2 = pkfma(wx, rb0, A2);  B2 = pkfma(wy, rb0, B2);
            A3 = pkfma(wx, rb1, A3);  B3 = pkfma(wy, rb1, B3);
            A0 = pkfma(wz, rc0, A0);  B0 = pkfma(ww, rc0, B0);
            A1 = pkfma(wz, rc1, A1);  B1 = pkfma(ww, rc1, B1);
            A2 = pkfma(wz, rd0, A2);  B2 = pkfma(ww, rd0, B2);
            A3 = pkfma(wz, rd1, A3);  B3 = pkfma(ww, rd1, B3);
        }
        const v2f h0 = {A0.x - B0.y, A0.y + B0.x};
        const v2f h1 = {A1.x - B1.y, A1.y + B1.x};
        const v2f h2 = {A2.x - B2.y, A2.y + B2.x};
        const v2f h3 = {A3.x - B3.y, A3.y + B3.x};

        // ---- P phase, fused with both shfl reduction rounds
        float2 s4[4];
#pragma unroll
        for (int pr = 0; pr < 4; ++pr) {
            float2 qq[2];
#pragma unroll
            for (int hh = 0; hh < 2; ++hh) {
                const int i = pr + 4 * hh;          // mp pair (i, i+8)
                const int ms = i & 7;               // == (i+8)&7
                const float4 waA = WvS4[buf][f][i][(2 * g) ^ ms];
                const float4 wbA = WvS4[buf][f][i][(2 * g + 1) ^ ms];
                v2f PA = {0,0}, PB = {0,0};
                PA = pkfma((v2f){waA.x, waA.x}, h0, PA);  PB = pkfma((v2f){waA.y, waA.y}, h0, PB);
                PA = pkfma((v2f){waA.z, waA.z}, h1, PA);  PB = pkfma((v2f){waA.w, waA.w}, h1, PB);
                PA = pkfma((v2f){wbA.x, wbA.x}, h2, PA);  PB = pkfma((v2f){wbA.y, wbA.y}, h2, PB);
                PA = pkfma((v2f){wbA.z, wbA.z}, h3, PA);  PB = pkfma((v2f){wbA.w, wbA.w}, h3, PB);
                const float2 pa = make_float2(PA.x + PB.y, PA.y - PB.x);
                const float4 waB = WvS4[buf][f][i + 8][(2 * g) ^ ms];
                const float4 wbB = WvS4[buf][f][i + 8][(2 * g + 1) ^ ms];
                v2f QA = {0,0}, QB = {0,0};
                QA = pkfma((v2f){waB.x, waB.x}, h0, QA);  QB = pkfma((v2f){waB.y, waB.y}, h0, QB);
                QA = pkfma((v2f){waB.z, waB.z}, h1, QA);  QB = pkfma((v2f){waB.w, waB.w}, h1, QB);
                QA = pkfma((v2f){wbB.x, wbB.x}, h2, QA);  QB = pkfma((v2f){wbB.y, wbB.y}, h2, QB);
                QA = pkfma((v2f){wbB.z, wbB.z}, h3, QA);  QB = pkfma((v2f){wbB.w, wbB.w}, h3, QB);
                const float2 pb = make_float2(QA.x + QB.y, QA.y - QB.x);
                const float sx = (g & 1) ? pa.x : pb.x;
                const float sy = (g & 1) ? pa.y : pb.y;
                const float rx = __shfl_xor(sx, 1, 64);
                const float ry = __shfl_xor(sy, 1, 64);
                const float kx = (g & 1) ? pb.x : pa.x;
                const float ky = (g & 1) ? pb.y : pa.y;
                qq[hh] = make_float2(kx + rx, ky + ry);
            }
            const float sx = (g & 2) ? qq[0].x : qq[1].x;
            const float sy = (g & 2) ? qq[0].y : qq[1].y;
            const float rx = __shfl_xor(sx, 2, 64);
            const float ry = __shfl_xor(sy, 2, 64);
            const float kx = (g & 2) ? qq[1].x : qq[0].x;
            const float ky = (g & 2) ? qq[1].y : qq[0].y;
            s4[pr] = make_float2(kx + rx, ky + ry);
        }
        const int mpbase = 8 * (g & 1) + 4 * ((g >> 1) & 1);

        // ---- SS_f partial write (swizzled) + diagonal
        {
            const int u0 = mpbase >> 1;
            SSp4[f][r][u0 ^ rs]       = make_float4(s4[0].x, s4[0].y, s4[1].x, s4[1].y);
            SSp4[f][r][(u0 + 1) ^ rs] = make_float4(s4[2].x, s4[2].y, s4[3].x, s4[3].y);
        }
        {
            const int Q = r >> 2;
            const int gh = ((Q & 1) << 1) | (Q >> 1);   // lane-g holding mp==r
            if (g == gh) {
                float dv = s4[0].x;
                if ((r & 3) == 1) dv = s4[1].x;
                if ((r & 3) == 2) dv = s4[2].x;
                if ((r & 3) == 3) dv = s4[3].x;
                dvalS[f * 16 + r] = dv;
            }
        }
        __syncthreads();   // barrier A: SS/diag visible; WvS[buf] reads done

        // ---- tail: red' (waves 0-3), Z sums (waves 8-15), Wv(t+1) (all)
        if (t + 1 < SEQ) {
            const int nbuf = buf ^ 1;
            compute_wv_piece(wrBase, &w16S[t + 1][0],
                             &WvS4[nbuf][f][r][(2 * g) ^ rs],
                             &WvS4[nbuf][f][r][(2 * g + 1) ^ rs]);
        }
        if (tid < 256) {
            const int m = tid >> 4, mp = tid & 15;
            const float2* S2 = (const float2*)SSp4;
            v2f sv = {0.0f, 0.0f};
            const int ci = mp ^ ((m & 7) * 2);
#pragma unroll
            for (int ff = 0; ff < 16; ++ff) {
                const float2 v = S2[(ff * 16 + m) * 16 + ci];
                sv += (v2f){v.x, v.y};
            }
            const float dp = dephS[__popc(m ^ mp)];
            redS[m][mp] = make_float2(sv.x * dp, sv.y * dp);
        } else if (f >= 8) {
            const int w = f - 8;
            const float4 dv = ((const float4*)dvalS)[lane];
            float v = 0.0f;
#pragma unroll
            for (int i = 0; i < 4; ++i) {
                const int d = 4 * lane + i;
                const float val = (i == 0) ? dv.x : (i == 1) ? dv.y : (i == 2) ? dv.z : dv.w;
                v += ((d >> (7 - w)) & 1) ? -val : val;
            }
#pragma unroll
            for (int off = 32; off >= 1; off >>= 1) v += __shfl_xor(v, off, 64);
            if (lane == 0) featsS[t * 8 + w] = v;
        }
        __syncthreads();   // barrier B: red'/feats/Wv(t+1) visible
    }

    // ---- FC epilogue
    if (tid < NCLASS) {
        float acc = fc_b[tid];
#pragma unroll
        for (int qq = 0; qq < 64; ++qq)
            acc = fmaf(featsS[qq], fc_w[tid * 64 + qq], acc);
        out[b * NCLASS + tid] = acc;
    }
}

extern "C" void kernel_launch(void* const* d_in, const int* in_sizes, int n_in,
                              void* d_out, int out_size, void* d_ws, size_t ws_size,
                              hipStream_t stream) {
    (void)in_sizes; (void)n_in; (void)out_size; (void)ws_size;
    const float* x    = (const float*)d_in[0];
    const float* qrot = (const float*)d_in[1];
    const float* qent = (const float*)d_in[2];
    const float* graw = (const float*)d_in[3];
    const float* fcw  = (const float*)d_in[4];
    const float* fcb  = (const float*)d_in[5];
    float* out = (float*)d_out;

    float4* Wr4 = (float4*)d_ws;   // 512 KB row-major W (float4 col-pairs)

    build_w_kernel<<<64, 256, 0, stream>>>(qrot, qent, Wr4);
    evolve_kernel<<<64, 1024, 0, stream>>>(x, graw, fcw, fcb, Wr4, out);
}

// Round 9
// 79.476 us; speedup vs baseline: 2.2390x; 2.2390x over previous
//
#include <hip/hip_runtime.h>
#include <math.h>

#define SEQ 8
#define NCLASS 10

typedef float v2f __attribute__((ext_vector_type(2)));

__device__ __forceinline__ v2f pkfma(v2f a, v2f b, v2f c) {
    return __builtin_elementwise_fma(a, b, c);
}

__device__ inline float2 cmul(float2 a, float2 b) {
    return make_float2(a.x * b.x - a.y * b.y, a.x * b.y + a.y * b.x);
}

// async global->LDS, 16B per lane: dest = lds_base(wave-uniform) + lane*16
__device__ __forceinline__ void gload_lds16(const float4* g, float4* l) {
    __builtin_amdgcn_global_load_lds(
        (const __attribute__((address_space(1))) void*)g,
        (__attribute__((address_space(3))) void*)l, 16, 0, 0);
}

// ---------------------------------------------------------------------------
// build_w: W = G32...G1 stored transposed WT[c*256 + r] = W[r][c].
// One WAVE per column, column in registers (4 complex/lane); gate params
// hoisted to LDS (R7 — removes serialized loads + transcendentals from chain).
// ---------------------------------------------------------------------------
__global__ __launch_bounds__(256) void build_w_kernel(
    const float* __restrict__ qrot, const float* __restrict__ qent,
    float2* __restrict__ WT) {
    __shared__ float4 US[32][2];
    __shared__ int    metaS[32];
    const int t = threadIdx.x;
    if (t < 32) {
        const int l = t >> 4, wi = t & 15;
        int bc = -1, qt;
        const float* p;
        if (wi < 8) { qt = wi; p = qrot + (l * 8 + wi) * 3; }
        else { const int qc = wi - 8; qt = (qc + 1) & 7; p = qent + (l * 8 + qc) * 3; bc = 7 - qc; }
        const float th = p[0], ph = p[1], lam = p[2];
        const float c = cosf(0.5f * th), s = sinf(0.5f * th);
        US[t][0] = make_float4(c, 0.0f, -cosf(lam) * s, -sinf(lam) * s);
        US[t][1] = make_float4(cosf(ph) * s, sinf(ph) * s,
                               cosf(ph + lam) * c, sinf(ph + lam) * c);
        metaS[t] = ((bc + 1) << 8) | (7 - qt);
    }
    __syncthreads();

    const int lane = t & 63;
    const int col = blockIdx.x * 4 + (t >> 6);
    const int rbase = lane * 4;
    float2 a[4];
#pragma unroll
    for (int i = 0; i < 4; ++i)
        a[i] = make_float2((rbase + i) == col ? 1.0f : 0.0f, 0.0f);

    for (int g = 0; g < 32; ++g) {
        const int meta = metaS[g];
        const int bt = meta & 255;
        const int bcp1 = meta >> 8;          // 0 = no control
        const float4 u0 = US[g][0];
        const float4 u1 = US[g][1];
        const float2 U00 = make_float2(u0.x, u0.y);
        const float2 U01 = make_float2(u0.z, u0.w);
        const float2 U10 = make_float2(u1.x, u1.y);
        const float2 U11 = make_float2(u1.z, u1.w);
        const int mt = 1 << bt;
        if (bt >= 2) {
            const int pl = mt >> 2;
            const int side = (lane >> (bt - 2)) & 1;
            float2 br[4];
#pragma unroll
            for (int i = 0; i < 4; ++i) {
                br[i].x = __shfl_xor(a[i].x, pl, 64);
                br[i].y = __shfl_xor(a[i].y, pl, 64);
            }
#pragma unroll
            for (int i = 0; i < 4; ++i) {
                const int r = rbase + i;
                float2 na, tt;
                if (side) { na = cmul(U10, br[i]); tt = cmul(U11, a[i]); }
                else      { na = cmul(U00, a[i]); tt = cmul(U01, br[i]); }
                na.x += tt.x; na.y += tt.y;
                const bool act = (bcp1 == 0) || ((r >> (bcp1 - 1)) & 1);
                if (act) a[i] = na;
            }
        } else {
#pragma unroll
            for (int i0 = 0; i0 < 4; ++i0) {
                if (i0 & mt) continue;
                const int i1 = i0 | mt;
                const int r0 = rbase + i0;
                const bool act = (bcp1 == 0) || ((r0 >> (bcp1 - 1)) & 1);
                const float2 a0 = a[i0], a1 = a[i1];
                float2 n0 = cmul(U00, a0), t1 = cmul(U01, a1);
                n0.x += t1.x; n0.y += t1.y;
                float2 n1 = cmul(U10, a0), t2 = cmul(U11, a1);
                n1.x += t2.x; n1.y += t2.y;
                if (act) { a[i0] = n0; a[i1] = n1; }
            }
        }
    }
    float4* dst = (float4*)&WT[col * 256 + rbase];
    dst[0] = make_float4(a[0].x, a[0].y, a[1].x, a[1].y);
    dst[1] = make_float4(a[2].x, a[2].y, a[3].x, a[3].y);
}

// ---------------------------------------------------------------------------
// wv: Wv[I][j] = sum_k W[I][(j,k)] * w16[b,t,k], written as the SWIZZLED
// LDS image: elem (I, cols 2u..2u+1) at [(t*64+b)*2048 + I*8 + (u^(I&7))].
// R9: 2 batch elements per block (b, b+32) sharing the WT loads -> WT L2
// traffic halves (256MB -> 128MB); grid 512 -> 256 blocks.
// ---------------------------------------------------------------------------
__global__ __launch_bounds__(256) void wv_kernel(
    const float* __restrict__ x, const float2* __restrict__ WT,
    float4* __restrict__ WvT4) {
    __shared__ float w16s[2][16];
    __shared__ float2 sS[2][256][17];
    const int tid = threadIdx.x;
    const int t = blockIdx.x >> 5;
    const int bp = blockIdx.x & 31;      // pair id: handles b=bp and b=bp+32
    if (tid < 32) {
        const int pi = tid >> 4, k = tid & 15;
        const int bb = bp + 32 * pi;
        float prod = 1.0f;
#pragma unroll
        for (int i = 0; i < 4; ++i) {
            const float xv = x[(bb * SEQ + t) * 4 + i];
            prod *= ((k >> i) & 1) ? sqrtf(xv) : sqrtf(1.0f - xv);
        }
        w16s[pi][k] = prod;
    }
    __syncthreads();
    float w0[16], w1[16];
#pragma unroll
    for (int k = 0; k < 16; ++k) { w0[k] = w16s[0][k]; w1[k] = w16s[1][k]; }
    const float2* wrow = WT + tid;
#pragma unroll
    for (int j = 0; j < 16; ++j) {
        float2 a0 = make_float2(0.0f, 0.0f);
        float2 a1 = make_float2(0.0f, 0.0f);
#pragma unroll
        for (int k = 0; k < 16; ++k) {
            const float2 wv = wrow[(j * 16 + k) * 256];
            a0.x = fmaf(wv.x, w0[k], a0.x);
            a0.y = fmaf(wv.y, w0[k], a0.y);
            a1.x = fmaf(wv.x, w1[k], a1.x);
            a1.y = fmaf(wv.y, w1[k], a1.y);
        }
        sS[0][tid][j] = a0;
        sS[1][tid][j] = a1;
    }
    __syncthreads();
#pragma unroll
    for (int pi = 0; pi < 2; ++pi) {
        const int bb = bp + 32 * pi;
        float4* dst = WvT4 + (t * 64 + bb) * 2048;
#pragma unroll
        for (int s = 0; s < 8; ++s) {
            const int e0 = 2 * tid + 512 * s;
            const int I0 = e0 >> 4, j0 = e0 & 15;
            const int u = j0 >> 1;
            const float2 a = sS[pi][I0][j0];
            const float2 c = sS[pi][I0][j0 + 1];
            dst[(I0 << 3) | (u ^ (I0 & 7))] = make_float4(a.x, a.y, c.x, c.y);
        }
    }
}

// ---------------------------------------------------------------------------
// evolve: 64 blocks x 1024 threads; wave = traced index f (16 waves).
// Byte-identical to R7 (passed, absmax 0.0, ~26us): packed split-accumulator
// complex MACs, gload_lds double-buffered staging, swizzled LDS, 2 barriers.
// ---------------------------------------------------------------------------
__global__ __launch_bounds__(1024)
__attribute__((amdgpu_waves_per_eu(4, 4)))
void evolve_kernel(
    const float* __restrict__ g_raw_p,
    const float* __restrict__ fc_w, const float* __restrict__ fc_b,
    const float4* __restrict__ WvT4, float* __restrict__ out) {
    __shared__ float4 WvS4[2][16][16][8];   // [buf][f][row][u ^ (row&7)]
    __shared__ float4 SSp4[16][16][8];      // swizzled same way
    __shared__ float2 redS[16][16];
    __shared__ float dvalS[256];
    __shared__ float dephS[8];
    __shared__ float featsS[64];

    const int tid = threadIdx.x;
    const int b = blockIdx.x;
    const int f = tid >> 6;
    const int lane = tid & 63;
    const int r = lane >> 2;
    const int g = lane & 3;
    const int rs = r & 7;

    if (tid < 256) redS[tid >> 4][tid & 15] = make_float2(tid == 0 ? 1.0f : 0.0f, 0.0f);
    const float gg = log1pf(expf(g_raw_p[0]));   // softplus
    if (tid < 8) dephS[tid] = expf(-0.5f * gg * gg * (float)tid);

    // prologue: stage t=0 tile into buf 0 (async, linear dest = swizzled image)
    {
        const float4* src = WvT4 + b * 2048 + f * 128;
        gload_lds16(src + lane, &WvS4[0][f][0][0]);
        gload_lds16(src + 64 + lane, &WvS4[0][f][8][0]);
    }
    __syncthreads();

    for (int t = 0; t < SEQ; ++t) {
        const int buf = t & 1;
        // ---- issue next tile's async stage first (completes by barrier A)
        if (t + 1 < SEQ) {
            const float4* src = WvT4 + ((t + 1) * 64 + b) * 2048 + f * 128;
            gload_lds16(src + lane, &WvS4[buf ^ 1][f][0][0]);
            gload_lds16(src + 64 + lane, &WvS4[buf ^ 1][f][8][0]);
        }

        // ---- H phase: split accumulators, packed FMAs
        v2f A0 = {0,0}, A1 = {0,0}, A2 = {0,0}, A3 = {0,0};
        v2f B0 = {0,0}, B1 = {0,0}, B2 = {0,0}, B3 = {0,0};
#pragma unroll
        for (int u = 0; u < 8; ++u) {
            const float4 wv = WvS4[buf][f][r][u ^ rs];   // Wv[r][2u], Wv[r][2u+1]
            const float4 ra = *(const float4*)&redS[2 * u][4 * g];
            const float4 rb = *(const float4*)&redS[2 * u][4 * g + 2];
            const float4 rc = *(const float4*)&redS[2 * u + 1][4 * g];
            const float4 rd = *(const float4*)&redS[2 * u + 1][4 * g + 2];
            const v2f wx = {wv.x, wv.x}, wy = {wv.y, wv.y};
            const v2f wz = {wv.z, wv.z}, ww = {wv.w, wv.w};
            const v2f ra0 = {ra.x, ra.y}, ra1 = {ra.z, ra.w};
            const v2f rb0 = {rb.x, rb.y}, rb1 = {rb.z, rb.w};
            const v2f rc0 = {rc.x, rc.y}, rc1 = {rc.z, rc.w};
            const v2f rd0 = {rd.x, rd.y}, rd1 = {rd.z, rd.w};
            A0 = pkfma(wx, ra0, A0);  B0 = pkfma(wy, ra0, B0);
            A1 = pkfma(wx, ra1, A1);  B1 = pkfma(wy, ra1, B1);
            A2 = pkfma(wx, rb0, A2);  B2 = pkfma(wy, rb0, B2);
            A3 = pkfma(wx, rb1, A3);  B3 = pkfma(wy, rb1, B3);
            A0 = pkfma(wz, rc0, A0);  B0 = pkfma(ww, rc0, B0);
            A1 = pkfma(wz, rc1, A1);  B1 = pkfma(ww, rc1, B1);
            A2 = pkfma(wz, rd0, A2);  B2 = pkfma(ww, rd0, B2);
            A3 = pkfma(wz, rd1, A3);  B3 = pkfma(ww, rd1, B3);
        }
        const v2f h0 = {A0.x - B0.y, A0.y + B0.x};
        const v2f h1 = {A1.x - B1.y, A1.y + B1.x};
        const v2f h2 = {A2.x - B2.y, A2.y + B2.x};
        const v2f h3 = {A3.x - B3.y, A3.y + B3.x};

        // ---- P phase, fused with both shfl reduction rounds
        float2 s4[4];
#pragma unroll
        for (int pr = 0; pr < 4; ++pr) {
            float2 qq[2];
#pragma unroll
            for (int hh = 0; hh < 2; ++hh) {
                const int i = pr + 4 * hh;          // mp pair (i, i+8)
                const int ms = i & 7;               // == (i+8)&7
                const float4 waA = WvS4[buf][f][i][(2 * g) ^ ms];
                const float4 wbA = WvS4[buf][f][i][(2 * g + 1) ^ ms];
                v2f PA = {0,0}, PB = {0,0};
                PA = pkfma((v2f){waA.x, waA.x}, h0, PA);  PB = pkfma((v2f){waA.y, waA.y}, h0, PB);
                PA = pkfma((v2f){waA.z, waA.z}, h1, PA);  PB = pkfma((v2f){waA.w, waA.w}, h1, PB);
                PA = pkfma((v2f){wbA.x, wbA.x}, h2, PA);  PB = pkfma((v2f){wbA.y, wbA.y}, h2, PB);
                PA = pkfma((v2f){wbA.z, wbA.z}, h3, PA);  PB = pkfma((v2f){wbA.w, wbA.w}, h3, PB);
                const float2 pa = make_float2(PA.x + PB.y, PA.y - PB.x);
                const float4 waB = WvS4[buf][f][i + 8][(2 * g) ^ ms];
                const float4 wbB = WvS4[buf][f][i + 8][(2 * g + 1) ^ ms];
                v2f QA = {0,0}, QB = {0,0};
                QA = pkfma((v2f){waB.x, waB.x}, h0, QA);  QB = pkfma((v2f){waB.y, waB.y}, h0, QB);
                QA = pkfma((v2f){waB.z, waB.z}, h1, QA);  QB = pkfma((v2f){waB.w, waB.w}, h1, QB);
                QA = pkfma((v2f){wbB.x, wbB.x}, h2, QA);  QB = pkfma((v2f){wbB.y, wbB.y}, h2, QB);
                QA = pkfma((v2f){wbB.z, wbB.z}, h3, QA);  QB = pkfma((v2f){wbB.w, wbB.w}, h3, QB);
                const float2 pb = make_float2(QA.x + QB.y, QA.y - QB.x);
                const float sx = (g & 1) ? pa.x : pb.x;
                const float sy = (g & 1) ? pa.y : pb.y;
                const float rx = __shfl_xor(sx, 1, 64);
                const float ry = __shfl_xor(sy, 1, 64);
                const float kx = (g & 1) ? pb.x : pa.x;
                const float ky = (g & 1) ? pb.y : pa.y;
                qq[hh] = make_float2(kx + rx, ky + ry);
            }
            const float sx = (g & 2) ? qq[0].x : qq[1].x;
            const float sy = (g & 2) ? qq[0].y : qq[1].y;
            const float rx = __shfl_xor(sx, 2, 64);
            const float ry = __shfl_xor(sy, 2, 64);
            const float kx = (g & 2) ? qq[1].x : qq[0].x;
            const float ky = (g & 2) ? qq[1].y : qq[0].y;
            s4[pr] = make_float2(kx + rx, ky + ry);
        }
        const int mpbase = 8 * (g & 1) + 4 * ((g >> 1) & 1);

        // ---- SS_f partial write (swizzled) + diagonal
        {
            const int u0 = mpbase >> 1;
            SSp4[f][r][u0 ^ rs]       = make_float4(s4[0].x, s4[0].y, s4[1].x, s4[1].y);
            SSp4[f][r][(u0 + 1) ^ rs] = make_float4(s4[2].x, s4[2].y, s4[3].x, s4[3].y);
        }
        {
            const int Q = r >> 2;
            const int gh = ((Q & 1) << 1) | (Q >> 1);   // lane-g holding mp==r
            if (g == gh) {
                float dv = s4[0].x;
                if ((r & 3) == 1) dv = s4[1].x;
                if ((r & 3) == 2) dv = s4[2].x;
                if ((r & 3) == 3) dv = s4[3].x;
                dvalS[f * 16 + r] = dv;
            }
        }
        __syncthreads();   // barrier A: SS/diag visible; async stage drained

        // ---- tail: waves 0-3 -> red'; waves 8-15 -> Z expectations
        if (tid < 256) {
            const int m = tid >> 4, mp = tid & 15;
            const float2* S2 = (const float2*)SSp4;
            v2f sv = {0.0f, 0.0f};
            const int ci = mp ^ ((m & 7) * 2);
#pragma unroll
            for (int ff = 0; ff < 16; ++ff) {
                const float2 v = S2[(ff * 16 + m) * 16 + ci];
                sv += (v2f){v.x, v.y};
            }
            const float dp = dephS[__popc(m ^ mp)];
            redS[m][mp] = make_float2(sv.x * dp, sv.y * dp);
        } else if (f >= 8) {
            const int w = f - 8;
            const float4 dv = ((const float4*)dvalS)[lane];
            float v = 0.0f;
#pragma unroll
            for (int i = 0; i < 4; ++i) {
                const int d = 4 * lane + i;
                const float val = (i == 0) ? dv.x : (i == 1) ? dv.y : (i == 2) ? dv.z : dv.w;
                v += ((d >> (7 - w)) & 1) ? -val : val;
            }
#pragma unroll
            for (int off = 32; off >= 1; off >>= 1) v += __shfl_xor(v, off, 64);
            if (lane == 0) featsS[t * 8 + w] = v;
        }
        __syncthreads();   // barrier B: red'/feats visible for next step
    }

    // ---- FC epilogue
    if (tid < NCLASS) {
        float acc = fc_b[tid];
#pragma unroll
        for (int qq = 0; qq < 64; ++qq)
            acc = fmaf(featsS[qq], fc_w[tid * 64 + qq], acc);
        out[b * NCLASS + tid] = acc;
    }
}

extern "C" void kernel_launch(void* const* d_in, const int* in_sizes, int n_in,
                              void* d_out, int out_size, void* d_ws, size_t ws_size,
                              hipStream_t stream) {
    (void)in_sizes; (void)n_in; (void)out_size; (void)ws_size;
    const float* x    = (const float*)d_in[0];
    const float* qrot = (const float*)d_in[1];
    const float* qent = (const float*)d_in[2];
    const float* graw = (const float*)d_in[3];
    const float* fcw  = (const float*)d_in[4];
    const float* fcb  = (const float*)d_in[5];
    float* out = (float*)d_out;

    float2* WT  = (float2*)d_ws;                      // 512 KB
    float4* WvT = (float4*)((char*)d_ws + 524288);    // 16 MB swizzled image

    build_w_kernel<<<64, 256, 0, stream>>>(qrot, qent, WT);
    wv_kernel<<<256, 256, 0, stream>>>(x, WT, WvT);
    evolve_kernel<<<64, 1024, 0, stream>>>(graw, fcw, fcb, WvT, out);
}